// Round 1
// baseline (799.382 us; speedup 1.0000x reference)
//
#include <hip/hip_runtime.h>

#define DT_F 0.01f
#define EPS_F 1e-5f

__device__ __forceinline__ float rl(float v, int l) {
  return __int_as_float(__builtin_amdgcn_readlane(__float_as_int(v), l));
}
__device__ __forceinline__ float sigm(float x) { return 1.0f / (1.0f + __expf(-x)); }
__device__ __forceinline__ float tanhf_fast(float x) {
  float e = __expf(-2.0f * fabsf(x));
  float t = (1.0f - e) / (1.0f + e);
  return x < 0.0f ? -t : t;
}

// evtab[k*B + sid] = (last obs index in event k's window with sample_ids==sid) + 1, or 0.
__global__ void build_evtab_kernel(const int* __restrict__ sample_ids,
                                   const int* __restrict__ time_ptr,
                                   int* __restrict__ evtab, int B, int ope) {
  int k = blockIdx.x;
  int base = time_ptr[k];
  for (int t = threadIdx.x; t < ope; t += blockDim.x) {
    int obs = base + t;
    int sid = sample_ids[obs];
    atomicMax(&evtab[k * B + sid], obs + 1);   // last occurrence wins (max obs)
  }
}

// One wave per sample. lane i holds h[i]. ODE weights in registers (row per lane).
__global__ __launch_bounds__(256, 1) void evolve_kernel(
    const float* __restrict__ time_uniq,
    const float* __restrict__ X,
    const float* __restrict__ covs,
    const float* __restrict__ cov_W1, const float* __restrict__ cov_b1,
    const float* __restrict__ cov_W2, const float* __restrict__ cov_b2,
    const float* __restrict__ gb_Wih, const float* __restrict__ gb_Whh,
    const float* __restrict__ gb_bih, const float* __restrict__ gb_bhh,
    const float* __restrict__ gx_b,
    const float* __restrict__ ghr_W, const float* __restrict__ ghz_W,
    const float* __restrict__ ghh_W,
    const int* __restrict__ evtab,
    float* __restrict__ hpath,
    int B, int NE, int n_steps, int IN, int COV)
{
  __shared__ float sWhh[64 * 192];   // sWhh[j*192 + row] = gb_Whh[row*64 + j]  (48KB)
  __shared__ float sWih[8 * 192];    // sWih[k*192 + row] = gb_Wih[row*IN + k]  (6KB)
  __shared__ int   sStep[1024];      // step at which event e fires             (4KB)

  for (int idx = threadIdx.x; idx < 192 * 64; idx += blockDim.x) {
    int row = idx >> 6, j = idx & 63;
    sWhh[j * 192 + row] = gb_Whh[idx];
  }
  for (int idx = threadIdx.x; idx < 192 * IN; idx += blockDim.x) {
    int row = idx / IN, kk = idx - row * IN;
    sWih[kk * 192 + row] = gb_Wih[idx];
  }
  // earliest step f_e with (float)k*DT + EPS >= time_uniq[e], exact fp32 semantics
  for (int e = threadIdx.x; e < NE && e < 1024; e += blockDim.x) {
    float tu = time_uniq[e];
    int k0 = (int)floorf((tu - EPS_F) * 100.0f) - 2;
    if (k0 < 0) k0 = 0;
    while ((float)k0 * DT_F + EPS_F < tu) ++k0;
    sStep[e] = k0;
  }
  __syncthreads();
  if (threadIdx.x == 0) {  // enforce <=1 event per step, in order
    int prev = -1;
    int ne = NE < 1024 ? NE : 1024;
    for (int e = 0; e < ne; ++e) {
      int s = sStep[e];
      if (s < prev + 1) s = prev + 1;
      sStep[e] = s;
      prev = s;
    }
  }
  __syncthreads();

  int wid = threadIdx.x >> 6, lane = threadIdx.x & 63;
  int b = blockIdx.x * 4 + wid;
  if (b >= B) return;

  // ---- h0 = tanh(relu(covs @ W1^T + b1) @ W2^T + b2) ----
  float cacc = cov_b1[lane];
  for (int kk = 0; kk < COV; ++kk)
    cacc = fmaf(covs[b * COV + kk], cov_W1[lane * COV + kk], cacc);
  float cl = fmaxf(cacc, 0.0f);
  float hacc = cov_b2[lane];
#pragma unroll
  for (int j = 0; j < 64; ++j)
    hacc = fmaf(rl(cl, j), cov_W2[lane * 64 + j], hacc);
  float h = tanhf_fast(hacc);

  // ---- ODE weights into registers: lane's row of each 64x64 matrix ----
  float4 WR[16], WZ[16], WH[16];
  {
    const float4* pr = (const float4*)(ghr_W + lane * 64);
    const float4* pz = (const float4*)(ghz_W + lane * 64);
    const float4* ph = (const float4*)(ghh_W + lane * 64);
#pragma unroll
    for (int q = 0; q < 16; ++q) { WR[q] = pr[q]; WZ[q] = pz[q]; WH[q] = ph[q]; }
  }
  float bihr = gb_bih[lane], bihz = gb_bih[64 + lane], bihn = gb_bih[128 + lane];
  float bhhr = gb_bhh[lane], bhhz = gb_bhh[64 + lane], bhhn = gb_bhh[128 + lane];
  float xr = gx_b[lane], xz = gx_b[64 + lane], xh = gx_b[128 + lane];

  int e_next = 0;
  int s_next = (NE > 0) ? sStep[0] : 0x7fffffff;
  int v_next = (NE > 0) ? evtab[b] : 0;

#pragma unroll 1
  for (int k = 0; k < n_steps; ++k) {
    if (k == s_next) {                       // wave-uniform
      if (v_next > 0) {                      // wave-uniform (same address per lane)
        int obs = v_next - 1;
        const float* xp = X + (long)obs * IN;
        float gir = bihr, giz = bihz, gin = bihn;
        for (int kk = 0; kk < IN; ++kk) {
          float xv = xp[kk];
          gir = fmaf(sWih[kk * 192 + lane], xv, gir);
          giz = fmaf(sWih[kk * 192 + 64 + lane], xv, giz);
          gin = fmaf(sWih[kk * 192 + 128 + lane], xv, gin);
        }
        float ghrv = bhhr, ghzv = bhhz, ghnv = bhhn;
#pragma unroll
        for (int j = 0; j < 64; ++j) {
          float hj = rl(h, j);
          ghrv = fmaf(sWhh[j * 192 + lane], hj, ghrv);
          ghzv = fmaf(sWhh[j * 192 + 64 + lane], hj, ghzv);
          ghnv = fmaf(sWhh[j * 192 + 128 + lane], hj, ghnv);
        }
        float r = sigm(gir + ghrv);
        float z = sigm(giz + ghzv);
        float n = tanhf_fast(gin + r * ghnv);
        h = (1.0f - z) * n + z * h;
      }
      ++e_next;
      if (e_next < NE) {
        s_next = sStep[e_next];
        v_next = evtab[(long)e_next * B + b];   // prefetch for future step
      } else {
        s_next = 0x7fffffff;
      }
    }

    hpath[((long)k * B + b) * 64 + lane] = h;   // h_rec (post-event, pre-ODE)

    // ---- GRU-ODE step ----
    float ar = xr, az = xz;
#pragma unroll
    for (int q = 0; q < 16; ++q) {
      float h0v = rl(h, 4 * q + 0), h1v = rl(h, 4 * q + 1);
      float h2v = rl(h, 4 * q + 2), h3v = rl(h, 4 * q + 3);
      ar = fmaf(WR[q].x, h0v, ar); az = fmaf(WZ[q].x, h0v, az);
      ar = fmaf(WR[q].y, h1v, ar); az = fmaf(WZ[q].y, h1v, az);
      ar = fmaf(WR[q].z, h2v, ar); az = fmaf(WZ[q].z, h2v, az);
      ar = fmaf(WR[q].w, h3v, ar); az = fmaf(WZ[q].w, h3v, az);
    }
    float r = sigm(ar), z = sigm(az);
    float rh = r * h;
    float au = xh;
#pragma unroll
    for (int q = 0; q < 16; ++q) {
      float h0v = rl(rh, 4 * q + 0), h1v = rl(rh, 4 * q + 1);
      float h2v = rl(rh, 4 * q + 2), h3v = rl(rh, 4 * q + 3);
      au = fmaf(WH[q].x, h0v, au);
      au = fmaf(WH[q].y, h1v, au);
      au = fmaf(WH[q].z, h2v, au);
      au = fmaf(WH[q].w, h3v, au);
    }
    float u = tanhf_fast(au);
    h = h + DT_F * (1.0f - z) * (u - h);
  }
  hpath[((long)n_steps * B + b) * 64 + lane] = h;   // h_last
}

// out[row] = relu(h[row] @ W1^T + b1) @ W2^T + b2, rows = (n_steps+1)*B
__global__ __launch_bounds__(256, 2) void head_kernel(
    const float* __restrict__ hpath, const float* __restrict__ W1,
    const float* __restrict__ b1, const float* __restrict__ W2,
    const float* __restrict__ b2, float* __restrict__ out, long nrows)
{
  __shared__ __align__(16) float sW1[64 * 128];  // sW1[j*128 + oc] = W1[oc*64 + j]
  __shared__ __align__(16) float sH[64 * 128];   // sH[j*128 + r]  = h[row0+r][j]
  int tid = threadIdx.x;
  for (int idx = tid; idx < 128 * 64; idx += 256) {
    int oc = idx >> 6, j = idx & 63;
    sW1[j * 128 + oc] = W1[idx];
  }
  long row0 = (long)blockIdx.x * 128;
  for (int idx = tid; idx < 128 * 64; idx += 256) {
    int r = idx >> 6, j = idx & 63;
    long row = row0 + r;
    sH[j * 128 + r] = (row < nrows) ? hpath[row * 64 + j] : 0.0f;
  }
  __syncthreads();

  int tr = tid >> 4, tc = tid & 15;
  int r0 = tr * 8, oc0 = tc * 8;
  float acc[8][8];
#pragma unroll
  for (int s = 0; s < 8; ++s)
#pragma unroll
    for (int u = 0; u < 8; ++u) acc[s][u] = 0.0f;

#pragma unroll 4
  for (int j = 0; j < 64; ++j) {
    float4 ha = *(const float4*)&sH[j * 128 + r0];
    float4 hb = *(const float4*)&sH[j * 128 + r0 + 4];
    float4 wa = *(const float4*)&sW1[j * 128 + oc0];
    float4 wb = *(const float4*)&sW1[j * 128 + oc0 + 4];
    float hv[8] = {ha.x, ha.y, ha.z, ha.w, hb.x, hb.y, hb.z, hb.w};
    float wv[8] = {wa.x, wa.y, wa.z, wa.w, wb.x, wb.y, wb.z, wb.w};
#pragma unroll
    for (int s = 0; s < 8; ++s)
#pragma unroll
      for (int u = 0; u < 8; ++u)
        acc[s][u] = fmaf(hv[s], wv[u], acc[s][u]);
  }

  float p[8][2];
#pragma unroll
  for (int s = 0; s < 8; ++s) { p[s][0] = 0.0f; p[s][1] = 0.0f; }
#pragma unroll
  for (int u = 0; u < 8; ++u) {
    float b1v = b1[oc0 + u];
    float w2a = W2[oc0 + u];
    float w2b = W2[128 + oc0 + u];
#pragma unroll
    for (int s = 0; s < 8; ++s) {
      float o = fmaxf(acc[s][u] + b1v, 0.0f);
      p[s][0] = fmaf(o, w2a, p[s][0]);
      p[s][1] = fmaf(o, w2b, p[s][1]);
    }
  }
#pragma unroll
  for (int off = 1; off < 16; off <<= 1) {
#pragma unroll
    for (int s = 0; s < 8; ++s) {
      p[s][0] += __shfl_xor(p[s][0], off);
      p[s][1] += __shfl_xor(p[s][1], off);
    }
  }
  if (tc == 0) {
    float b20 = b2[0], b21 = b2[1];
#pragma unroll
    for (int s = 0; s < 8; ++s) {
      long row = row0 + r0 + s;
      if (row < nrows) {
        out[row * 2 + 0] = p[s][0] + b20;
        out[row * 2 + 1] = p[s][1] + b21;
      }
    }
  }
}

extern "C" void kernel_launch(void* const* d_in, const int* in_sizes, int n_in,
                              void* d_out, int out_size, void* d_ws, size_t ws_size,
                              hipStream_t stream) {
  const float* time_uniq  = (const float*)d_in[0];
  const int*   time_ptr   = (const int*)d_in[1];
  const float* X          = (const float*)d_in[2];
  const int*   sample_ids = (const int*)d_in[3];
  const float* covs       = (const float*)d_in[4];
  // d_in[5] = T (value derived from out_size instead)
  const float* cov_W1     = (const float*)d_in[6];
  const float* cov_b1     = (const float*)d_in[7];
  const float* cov_W2     = (const float*)d_in[8];
  const float* cov_b2     = (const float*)d_in[9];
  const float* gb_Wih     = (const float*)d_in[10];
  const float* gb_Whh     = (const float*)d_in[11];
  const float* gb_bih     = (const float*)d_in[12];
  const float* gb_bhh     = (const float*)d_in[13];
  // d_in[14] = gx_W (multiplied by zeros in reference; unused)
  const float* gx_b       = (const float*)d_in[15];
  const float* ghr_W      = (const float*)d_in[16];
  const float* ghz_W      = (const float*)d_in[17];
  const float* ghh_W      = (const float*)d_in[18];
  const float* out_W1     = (const float*)d_in[19];
  const float* out_b1     = (const float*)d_in[20];
  const float* out_W2     = (const float*)d_in[21];
  const float* out_b2     = (const float*)d_in[22];

  int NE   = in_sizes[0];
  int TOT  = in_sizes[3];
  int IN   = in_sizes[2] / TOT;
  int CH   = in_sizes[7];
  int COV  = in_sizes[6] / CH;
  int B    = in_sizes[4] / COV;
  int OUTD = in_sizes[22];
  int n_steps = out_size / (B * OUTD) - 1;
  int OPE  = TOT / NE;

  int* evtab = (int*)d_ws;
  size_t evbytes = (size_t)NE * (size_t)B * sizeof(int);
  size_t off = (evbytes + 255) & ~(size_t)255;
  float* hpath = (float*)((char*)d_ws + off);

  hipMemsetAsync(evtab, 0, evbytes, stream);
  build_evtab_kernel<<<NE, 256, 0, stream>>>(sample_ids, time_ptr, evtab, B, OPE);
  evolve_kernel<<<(B + 3) / 4, 256, 0, stream>>>(
      time_uniq, X, covs, cov_W1, cov_b1, cov_W2, cov_b2,
      gb_Wih, gb_Whh, gb_bih, gb_bhh, gx_b, ghr_W, ghz_W, ghh_W,
      evtab, hpath, B, NE, n_steps, IN, COV);
  long nrows = (long)(n_steps + 1) * B;
  int hb = (int)((nrows + 127) / 128);
  head_kernel<<<hb, 256, 0, stream>>>(hpath, out_W1, out_b1, out_W2, out_b2,
                                      (float*)d_out, nrows);
}